// Round 14
// baseline (552.233 us; speedup 1.0000x reference)
//
#include <hip/hip_runtime.h>
#include <math.h>

#define NN 20000
#define H 256
#define R 64
#define EE 320000
#define LN_EPS 1e-5f
#define NB 79    // ceil(NN/256)
#define GEDGE 256    // k_edge grid: 8 XCDs x 32 blocks, 12 waves each

using short8  = __attribute__((ext_vector_type(8))) short;
using ushort8 = __attribute__((ext_vector_type(8))) unsigned short;
using f32x4   = __attribute__((ext_vector_type(4))) float;
using half8   = __attribute__((ext_vector_type(8))) _Float16;
using half2v  = __attribute__((ext_vector_type(2))) _Float16;

typedef __attribute__((address_space(3))) unsigned int lds_uint;
typedef const __attribute__((address_space(1))) unsigned int glb_uint;

__device__ __forceinline__ float silu_f(float x) {
    return x * __builtin_amdgcn_rcpf(1.0f + __expf(-x));
}

// round-to-nearest-even fp32 -> bf16 (as ushort)
__device__ __forceinline__ unsigned short f2bf(float f) {
    unsigned u = __float_as_uint(f);
    u += 0x7fff + ((u >> 16) & 1);
    return (unsigned short)(u >> 16);
}
__device__ __forceinline__ float bf2f(unsigned short s) {
    return __uint_as_float(((unsigned)s) << 16);
}
// f32 <-> f16 (RNE) via v_cvt
__device__ __forceinline__ unsigned short f2h(float f) {
    unsigned r;
    asm("v_cvt_f16_f32 %0, %1" : "=v"(r) : "v"(f));
    return (unsigned short)r;
}
__device__ __forceinline__ float h2f(unsigned short h) {
    float f;
    asm("v_cvt_f32_f16 %0, %1" : "=v"(f) : "v"((unsigned)h));
    return f;
}

// dks f16 [16][256] per-wave slice: xor col bits[5:4] by row bits[3:2];
// 4-element runs at col%4==0 stay contiguous (XOR touches only bits >= 4).
__device__ __forceinline__ int dh_idx(int row, int col) {
    return row * 256 + (col ^ (((row >> 2) & 3) << 4));
}

// ---------------------------------------------------------------------------
// Combined prep (one launch, 226 blocks):
//  [0,128):   pack Wq/Wk/Wv (g folded) + Wo into split-bf16 MFMA B-fragments
//  [128,144): pack Wdk/Wdv as SINGLE-f16 fragment-linear images
//  [144,147): adjusted QKV biases
//  [147,226): zero hist
// ---------------------------------------------------------------------------
__global__ __launch_bounds__(256) void k_prep(
    const float* __restrict__ Wq, const float* __restrict__ Wk,
    const float* __restrict__ Wv, const float* __restrict__ Wo,
    const float* __restrict__ g,  const float* __restrict__ b,
    const float* __restrict__ bq, const float* __restrict__ bk, const float* __restrict__ bv,
    const float* __restrict__ Wdk, const float* __restrict__ Wdv,
    unsigned short* __restrict__ wqkv_p, unsigned short* __restrict__ wo_p,
    unsigned short* __restrict__ wdk_p,  unsigned short* __restrict__ wdv_p,
    float* __restrict__ bias3, int* __restrict__ hist)
{
    const int bid = blockIdx.x, t = threadIdx.x;
    if (bid < 128) {
        const int mat = bid >> 5;
        const float* W = mat == 0 ? Wq : (mat == 1 ? Wk : (mat == 2 ? Wv : Wo));
        unsigned short* out = (mat < 3) ? wqkv_p + (size_t)mat * 131072 : wo_p;
        const int fold = mat < 3;
        const int flat = (bid & 31) * 256 + t;           // [0, 8192)
        const int tile = flat >> 9;
        const int rem  = flat & 511;
        const int ks   = rem >> 6;
        const int lane = rem & 63;
        const int nl = lane & 15, quad = lane >> 4;
        const int h  = tile * 16 + nl;
        const int c0 = ks * 32 + quad * 8;
        short8 hi8, lo8;
        #pragma unroll
        for (int j = 0; j < 8; ++j) {
            float wv = W[(size_t)h * 256 + c0 + j];
            if (fold) wv *= g[c0 + j];
            const unsigned short hh = f2bf(wv);
            hi8[j] = (short)hh;
            lo8[j] = (short)f2bf(wv - bf2f(hh));
        }
        unsigned short* ob = out + ((size_t)(tile * 8 + ks)) * 1024;
        *(short8*)&ob[lane * 8] = hi8;
        *(short8*)&ob[512 + lane * 8] = lo8;
    } else if (bid < 144) {
        // single-f16 pack: value = W[hh*128 + tile*16+nl][ks*32+quad*8+j]
        // at img(mat) + hh*8192 + (tile*2+ks)*512 + lane*8 + j   (f16)
        const int flat = (bid - 128) * 256 + t;          // [0, 4096)
        const int mat  = flat >> 11;
        const int rem  = flat & 2047;
        const int hh   = rem >> 10;
        const int r2   = rem & 1023;
        const int tile = r2 >> 7;
        const int r3   = r2 & 127;
        const int ks   = r3 >> 6;
        const int lane = r3 & 63;
        const int nl = lane & 15, quad = lane >> 4;
        const float* W = mat == 0 ? Wdk : Wdv;
        unsigned short* out = (mat == 0 ? wdk_p : wdv_p)
                            + hh * 8192 + (tile * 2 + ks) * 512 + lane * 8;
        const float* wr = W + (size_t)(hh * 128 + tile * 16 + nl) * 64 + ks * 32 + quad * 8;
        const float4 w0 = *(const float4*)wr;
        const float4 w1 = *(const float4*)(wr + 4);
        const float zz[8] = {w0.x, w0.y, w0.z, w0.w, w1.x, w1.y, w1.z, w1.w};
        ushort8 p8;
        #pragma unroll
        for (int j = 0; j < 8; ++j) p8[j] = f2h(zz[j]);
        *(ushort8*)out = p8;
    } else if (bid < 147) {
        const int mat = bid - 144, h = t;
        const float* W  = mat == 0 ? Wq : (mat == 1 ? Wk : Wv);
        const float* bb = mat == 0 ? bq : (mat == 1 ? bk : bv);
        float s = 0.f;
        const float* wr = W + (size_t)h * 256;
        for (int c = 0; c < 256; c += 4) {
            const float4 w4 = *(const float4*)(wr + c);
            const float4 b4 = *(const float4*)(b + c);
            s += w4.x * b4.x + w4.y * b4.y + w4.z * b4.z + w4.w * b4.w;
        }
        bias3[mat * 256 + h] = bb[h] + s;
    } else {
        const int i = (bid - 147) * 256 + t;
        if (i < NN) hist[i] = 0;
    }
}

// ---------------------------------------------------------------------------
// K1: LayerNorm + QKV. Round-20: 6 waves per block -- wave w owns matrix
// (w>>1), tile half (w&1)x8. 7500 waves ~= 7.3/SIMD; per-wave serial path
// halved vs round-19. LN recomputed per wave (x row L2-hot, ~80 VALU ops).
// Numerics per output element identical.
// ---------------------------------------------------------------------------
__global__ __launch_bounds__(384) void k_ln_qkv(
    const float* __restrict__ x,
    const unsigned short* __restrict__ wqkv_p, const float* __restrict__ bias3,
    unsigned short* __restrict__ q, unsigned short* __restrict__ k,
    unsigned short* __restrict__ v)
{
    const int t = threadIdx.x;
    const int wave = t >> 6;             // 0..5
    const int mat  = wave >> 1;
    const int th   = wave & 1;           // tile half
    const int lane = t & 63;
    const int nl = lane & 15, quad = lane >> 4;
    const int nbase = blockIdx.x * 16;
    const int node = nbase + nl;
    const bool nv = node < NN;

    float xv[64];
    float sum = 0.f, sq = 0.f;
    {
        const float* xp = x + (size_t)node * H + quad * 8;
        #pragma unroll
        for (int ks = 0; ks < 8; ++ks) {
            float4 x0 = {0.f,0.f,0.f,0.f}, x1 = {0.f,0.f,0.f,0.f};
            if (nv) {
                x0 = *(const float4*)(xp + ks * 32);
                x1 = *(const float4*)(xp + ks * 32 + 4);
            }
            xv[ks*8+0]=x0.x; xv[ks*8+1]=x0.y; xv[ks*8+2]=x0.z; xv[ks*8+3]=x0.w;
            xv[ks*8+4]=x1.x; xv[ks*8+5]=x1.y; xv[ks*8+6]=x1.z; xv[ks*8+7]=x1.w;
            sum += x0.x+x0.y+x0.z+x0.w + x1.x+x1.y+x1.z+x1.w;
            sq  += x0.x*x0.x+x0.y*x0.y+x0.z*x0.z+x0.w*x0.w
                 + x1.x*x1.x+x1.y*x1.y+x1.z*x1.z+x1.w*x1.w;
        }
    }
    sum += __shfl_xor(sum, 16); sum += __shfl_xor(sum, 32);
    sq  += __shfl_xor(sq, 16);  sq  += __shfl_xor(sq, 32);
    const float mu  = sum * (1.0f / H);
    const float var = sq * (1.0f / H) - mu * mu;
    const float rs  = rsqrtf(var + LN_EPS);

    short8 a_hi[8], a_lo[8];
    #pragma unroll
    for (int ks = 0; ks < 8; ++ks) {
        #pragma unroll
        for (int j = 0; j < 8; ++j) {
            const float z = (xv[ks*8+j] - mu) * rs;
            const unsigned short hh = f2bf(z);
            a_hi[ks][j] = (short)hh;
            a_lo[ks][j] = (short)f2bf(z - bf2f(hh));
        }
    }

    unsigned short* outp = mat == 0 ? q : (mat == 1 ? k : v);
    const float* bp = bias3 + mat * 256;
    const unsigned short* wb = wqkv_p + (size_t)mat * 131072 + lane * 8;
    for (int tile = th * 8; tile < th * 8 + 8; ++tile) {
        const unsigned short* gb = wb + (size_t)tile * 8192;
        const float bbv = bp[tile * 16 + nl];
        f32x4 accH = {bbv, bbv, bbv, bbv};
        f32x4 accM = {0.f, 0.f, 0.f, 0.f};
        f32x4 accL = {0.f, 0.f, 0.f, 0.f};
        #pragma unroll
        for (int ks = 0; ks < 8; ++ks) {
            const short8 b_hi = *(const short8*)(gb + ks * 1024);
            const short8 b_lo = *(const short8*)(gb + ks * 1024 + 512);
            accH = __builtin_amdgcn_mfma_f32_16x16x32_bf16(a_hi[ks], b_hi, accH, 0, 0, 0);
            accM = __builtin_amdgcn_mfma_f32_16x16x32_bf16(a_lo[ks], b_hi, accM, 0, 0, 0);
            accL = __builtin_amdgcn_mfma_f32_16x16x32_bf16(a_hi[ks], b_lo, accL, 0, 0, 0);
        }
        const f32x4 acc = accH + accM + accL;
        #pragma unroll
        for (int r = 0; r < 4; ++r) {
            const int onode = nbase + quad * 4 + r;
            if (onode < NN)
                outp[(size_t)onode * H + tile * 16 + nl] = f2h(acc[r]);
        }
    }
}

// ---------------------------------------------------------------------------
// Counting sort of edges by dst: hist -> scan -> scatter
// ---------------------------------------------------------------------------
__global__ __launch_bounds__(256) void k_hist(const int* __restrict__ ei, int* __restrict__ hist) {
    int e = blockIdx.x * 256 + threadIdx.x;
    if (e < EE) atomicAdd(&hist[ei[EE + e]], 1);
}

__global__ __launch_bounds__(256) void k_scan1(const int* __restrict__ hist,
                                               int* __restrict__ cursor, int* __restrict__ bsum) {
    const int t = threadIdx.x, i = blockIdx.x * 256 + t;
    const int lane = t & 63, w = t >> 6;
    const int v = (i < NN) ? hist[i] : 0;
    int incl = v;
    #pragma unroll
    for (int off = 1; off < 64; off <<= 1) {
        int u = __shfl_up(incl, off);
        if (lane >= off) incl += u;
    }
    __shared__ int ws[4];
    if (lane == 63) ws[w] = incl;
    __syncthreads();
    int base = 0;
    #pragma unroll
    for (int j = 0; j < 4; ++j) if (j < w) base += ws[j];
    if (i < NN) cursor[i] = base + incl - v;
    if (t == 255) bsum[blockIdx.x] = base + incl;
}

__global__ __launch_bounds__(128) void k_scan2(int* __restrict__ bsum) {
    __shared__ int buf[128];
    const int t = threadIdx.x;
    const int v = (t < NB) ? bsum[t] : 0;
    buf[t] = v;
    __syncthreads();
    #pragma unroll
    for (int off = 1; off < 128; off <<= 1) {
        int add = (t >= off) ? buf[t - off] : 0;
        __syncthreads();
        buf[t] += add;
        __syncthreads();
    }
    if (t < NB) bsum[t] = buf[t] - v;
}

// scatter also materializes sorted src/dst/ew streams.
__global__ __launch_bounds__(256) void k_scatter(const int* __restrict__ ei,
                                                 const float* __restrict__ ew,
                                                 int* __restrict__ cursor,
                                                 const int* __restrict__ bsum,
                                                 int* __restrict__ perm,
                                                 int* __restrict__ srcs,
                                                 int* __restrict__ dsts,
                                                 float* __restrict__ ews) {
    int e = blockIdx.x * 256 + threadIdx.x;
    if (e < EE) {
        int s = ei[e];
        int d = ei[EE + e];
        int pos = atomicAdd(&cursor[d], 1) + bsum[d >> 8];
        perm[pos] = e;
        srcs[pos] = s;
        dsts[pos] = d;
        ews[pos] = ew[e];
    }
}

// ---------------------------------------------------------------------------
// K2: UNCHANGED from round-19 (251us, plateau: 2->3 waves/SIMD saturated).
// 12-wave 768-thread blocks, 160KB LDS, one barrier, independent waves.
// ---------------------------------------------------------------------------
__global__ __launch_bounds__(768, 3) void k_edge(
    const unsigned short* __restrict__ q16, const unsigned short* __restrict__ k16,
    const unsigned short* __restrict__ v16,
    const float* __restrict__ ea,
    const unsigned short* __restrict__ wdkv_p,   // wdk(16384) | wdv(16384) f16
    const float* __restrict__ bdk, const float* __restrict__ bdv,
    const int* __restrict__ perm, const int* __restrict__ srcs,
    const int* __restrict__ dsts, const float* __restrict__ ews,
    float* __restrict__ agg)
{
    __shared__ __align__(16) unsigned short wlds[4 * 8192];         // 64 KB
    __shared__ __align__(16) unsigned short dks_all[12 * 16 * 256]; // 96 KB

    const int t    = threadIdx.x;
    const int bi   = blockIdx.x;
    const int wave = t >> 6, lane = t & 63;
    const int nl = lane & 15, quad = lane >> 4;
    const int tx = lane & 31, ty2 = lane >> 5;
    const int h0 = tx * 4, e0l = ty2 * 8;

    // bijective XCD mapping: 256 blocks = 8 XCDs x 32; XCD x owns a
    // contiguous strip range (strip = 16 sorted edges; 20000 strips total,
    // first 32 wgids get 79 strips, rest 78).
    const int xcd = bi & 7, jj = bi >> 3;
    const int wgid = xcd * 32 + jj;
    const int sbase  = wgid * 78 + (wgid < 32 ? wgid : 32);
    const int scount = 78 + (wgid < 32 ? 1 : 0);

    unsigned short* dksw = dks_all + wave * 4096;

    // ---- stage all 64KB of weight images once ----
    {
        const ushort8* sp = (const ushort8*)wdkv_p + (t & 255);
        ushort8* dpw = (ushort8*)wlds + (t & 192);   // wave-uniform base
        if (t < 256) {
            #pragma unroll
            for (int c = 0; c < 16; ++c)
                __builtin_amdgcn_global_load_lds((glb_uint*)(sp + c * 256),
                                                 (lds_uint*)(dpw + c * 256), 16, 0, 0);
        }
    }
    __syncthreads();   // the ONLY block-wide barrier

    #define MFMA_DKS16(IMG, BIAS, HALF)                                               \
    {                                                                                 \
        const unsigned short* ib_ = wlds + (IMG) * 8192;                              \
        f32x4 accA[8];                                                                \
        _Pragma("unroll")                                                             \
        for (int tt = 0; tt < 8; ++tt) {                                              \
            const half8 b0 = *(const half8*)&ib_[(tt * 2 + 0) * 512 + lane * 8];      \
            const half8 b1 = *(const half8*)&ib_[(tt * 2 + 1) * 512 + lane * 8];      \
            const float bb = (BIAS)[(HALF) * 128 + tt * 16 + nl];                     \
            f32x4 acc = {bb, bb, bb, bb};                                             \
            acc = __builtin_amdgcn_mfma_f32_16x16x32_f16(af0, b0, acc, 0, 0, 0);      \
            acc = __builtin_amdgcn_mfma_f32_16x16x32_f16(af1, b1, acc, 0, 0, 0);      \
            accA[tt] = acc;                                                           \
        }                                                                             \
        _Pragma("unroll")                                                             \
        for (int tt = 0; tt < 8; ++tt)                                                \
            _Pragma("unroll")                                                         \
            for (int r = 0; r < 4; ++r)                                               \
                dksw[dh_idx(quad * 4 + r, (HALF) * 128 + tt * 16 + nl)] =             \
                    f2h(silu_f(accA[tt][r]));                                         \
    }

    // ---- up to 7 strip-iterations; per-wave independent, barrier-free ----
    for (int it = 0; it < 7; ++it) {
        const int sl = it * 12 + wave;
        if (sl >= scount) continue;
        const int eb2 = (sbase + sl) * 16;   // this wave's 16 edges

        // ea A-fragments as f16 (row nl = own edge)
        half8 af0, af1;
        {
            const int e = perm[eb2 + nl];
            const float* ap = ea + (size_t)e * R + quad * 8;
            const f32x4 x0 = *(const f32x4*)(ap);
            const f32x4 x1 = *(const f32x4*)(ap + 4);
            const f32x4 x2 = *(const f32x4*)(ap + 32);
            const f32x4 x3 = *(const f32x4*)(ap + 36);
            #pragma unroll
            for (int j2 = 0; j2 < 4; ++j2) {
                af0[j2]     = (_Float16)x0[j2];
                af0[j2 + 4] = (_Float16)x1[j2];
                af1[j2]     = (_Float16)x2[j2];
                af1[j2 + 4] = (_Float16)x3[j2];
            }
        }

        MFMA_DKS16(0, bdk, 0);
        MFMA_DKS16(1, bdk, 1);

        // my half-wave's 8 edges
        int srcr[8], dstr[8];
        #pragma unroll
        for (int i = 0; i < 8; ++i) {
            srcr[i] = srcs[eb2 + e0l + i];
            dstr[i] = dsts[eb2 + e0l + i];
        }

        // ---- pass A: pk_mul + fdot2; result reduced into every lane ----
        float att[8];
        {
            half2v qa, qb, qc, qd;
            int pd = -1;
            #pragma unroll
            for (int i = 0; i < 8; ++i) {
                const int d = dstr[i], s = srcr[i];
                if (d != pd) {
                    const uint2 qq0 = *(const uint2*)(q16 + (size_t)d * H + h0);
                    const uint2 qq1 = *(const uint2*)(q16 + (size_t)d * H + 128 + h0);
                    qa = __builtin_bit_cast(half2v, qq0.x);
                    qb = __builtin_bit_cast(half2v, qq0.y);
                    qc = __builtin_bit_cast(half2v, qq1.x);
                    qd = __builtin_bit_cast(half2v, qq1.y);
                    pd = d;
                }
                const uint2 kk0 = *(const uint2*)(k16 + (size_t)s * H + h0);
                const uint2 kk1 = *(const uint2*)(k16 + (size_t)s * H + 128 + h0);
                const uint2 dd0 = *(const uint2*)&dksw[dh_idx(e0l + i, h0)];
                const uint2 dd1 = *(const uint2*)&dksw[dh_idx(e0l + i, 128 + h0)];
                float part = 0.f;
                part = __builtin_amdgcn_fdot2(qa * __builtin_bit_cast(half2v, kk0.x),
                                              __builtin_bit_cast(half2v, dd0.x), part, false);
                part = __builtin_amdgcn_fdot2(qb * __builtin_bit_cast(half2v, kk0.y),
                                              __builtin_bit_cast(half2v, dd0.y), part, false);
                part = __builtin_amdgcn_fdot2(qc * __builtin_bit_cast(half2v, kk1.x),
                                              __builtin_bit_cast(half2v, dd1.x), part, false);
                part = __builtin_amdgcn_fdot2(qd * __builtin_bit_cast(half2v, kk1.y),
                                              __builtin_bit_cast(half2v, dd1.y), part, false);
                #pragma unroll
                for (int off = 16; off; off >>= 1) part += __shfl_xor(part, off);
                att[i] = part;   // xor-reduce: every lane holds the sum
            }
        }

        // finalize attn (redundant per lane; ews is an L2-hot sorted stream)
        #pragma unroll
        for (int i = 0; i < 8; ++i) {
            const float rr = ews[eb2 + e0l + i];
            const float cut = (rr < 5.0f) ? 0.5f * (__cosf(rr * 0.6283185307f) + 1.0f) : 0.0f;
            att[i] = silu_f(att[i]) * cut;
        }

        MFMA_DKS16(2, bdv, 0);
        MFMA_DKS16(3, bdv, 1);

        // ---- pass B: f16 v gathers, run-flush row-walk over 256 cols ----
        {
            float4 m0 = {0.f,0.f,0.f,0.f}, m1 = {0.f,0.f,0.f,0.f};
            int cur_d = -1;
            #pragma unroll
            for (int i = 0; i < 8; ++i) {
                const int d = dstr[i], s = srcr[i];
                const float a = att[i];
                const uint2 vv0 = *(const uint2*)(v16 + (size_t)s * H + h0);
                const uint2 vv1 = *(const uint2*)(v16 + (size_t)s * H + 128 + h0);
                const uint2 dd0 = *(const uint2*)&dksw[dh_idx(e0l + i, h0)];
                const uint2 dd1 = *(const uint2*)&dksw[dh_idx(e0l + i, 128 + h0)];
                const half2v w0 = __builtin_bit_cast(half2v, vv0.x) * __builtin_bit_cast(half2v, dd0.x);
                const half2v w1 = __builtin_bit_cast(half2v, vv0.y) * __builtin_bit_cast(half2v, dd0.y);
                const half2v w2 = __builtin_bit_cast(half2v, vv1.x) * __builtin_bit_cast(half2v, dd1.x);
                const half2v w3 = __builtin_bit_cast(half2v, vv1.y) * __builtin_bit_cast(half2v, dd1.y);
                if (d != cur_d) {
                    if (cur_d >= 0) {
                        float* dp = agg + (size_t)cur_d * H;
                        atomicAdd(dp + h0 + 0, m0.x); atomicAdd(dp + h0 + 1, m0.y);
                        atomicAdd(dp + h0 + 2, m0.z); atomicAdd(dp + h0 + 3, m0.w);
                        atomicAdd(dp + 128 + h0 + 0, m1.x); atomicAdd(dp + 128 + h0 + 1, m1.y);
                        atomicAdd(dp + 128 + h0 + 2, m1.z); atomicAdd(dp + 128 + h0 + 3, m1.w);
                    }
                    m0.x = (float)w0[0] * a; m0.y = (float)w0[1] * a;
                    m0.z = (float)w1[0] * a; m0.w = (float)w1[1] * a;
                    m1.x = (float)w2[0] * a; m1.y = (float)w2[1] * a;
                    m1.z = (float)w3[0] * a; m1.w = (float)w3[1] * a;
                    cur_d = d;
                } else {
                    m0.x += (float)w0[0] * a; m0.y += (float)w0[1] * a;
                    m0.z += (float)w1[0] * a; m0.w += (float)w1[1] * a;
                    m1.x += (float)w2[0] * a; m1.y += (float)w2[1] * a;
                    m1.z += (float)w3[0] * a; m1.w += (float)w3[1] * a;
                }
            }
            {
                float* dp = agg + (size_t)cur_d * H;
                atomicAdd(dp + h0 + 0, m0.x); atomicAdd(dp + h0 + 1, m0.y);
                atomicAdd(dp + h0 + 2, m0.z); atomicAdd(dp + h0 + 3, m0.w);
                atomicAdd(dp + 128 + h0 + 0, m1.x); atomicAdd(dp + 128 + h0 + 1, m1.y);
                atomicAdd(dp + 128 + h0 + 2, m1.z); atomicAdd(dp + 128 + h0 + 3, m1.w);
            }
        }
    }
    #undef MFMA_DKS16
}

// ---------------------------------------------------------------------------
// K3: out = x + agg @ Wo'^T + bo. Round-20: 4 waves per block, 4 tiles each
// (5000 waves ~= 4.9/SIMD).
// ---------------------------------------------------------------------------
__global__ __launch_bounds__(256) void k_out(
    const float* __restrict__ aggm, const unsigned short* __restrict__ wo_p,
    const float* __restrict__ bo, const float* __restrict__ x, float* __restrict__ out)
{
    const int t = threadIdx.x;
    const int wave = t >> 6;             // 0..3
    const int lane = t & 63;
    const int nl = lane & 15, quad = lane >> 4;
    const int nbase = blockIdx.x * 16;
    const int node = nbase + nl;
    const bool nv = node < NN;

    short8 a_hi[8], a_lo[8];
    {
        const float* ap = aggm + (size_t)node * H + quad * 8;
        #pragma unroll
        for (int ks = 0; ks < 8; ++ks) {
            float4 x0 = {0.f,0.f,0.f,0.f}, x1 = {0.f,0.f,0.f,0.f};
            if (nv) { x0 = *(const float4*)(ap + ks * 32); x1 = *(const float4*)(ap + ks * 32 + 4); }
            const float zz[8] = {x0.x,x0.y,x0.z,x0.w,x1.x,x1.y,x1.z,x1.w};
            #pragma unroll
            for (int j = 0; j < 8; ++j) {
                const unsigned short hh = f2bf(zz[j]);
                a_hi[ks][j] = (short)hh;
                a_lo[ks][j] = (short)f2bf(zz[j] - bf2f(hh));
            }
        }
    }
    for (int tile = wave * 4; tile < wave * 4 + 4; ++tile) {
        const unsigned short* gb = wo_p + (size_t)tile * 8192 + lane * 8;
        const float bbv = bo[tile * 16 + nl];
        f32x4 accH = {bbv, bbv, bbv, bbv};
        f32x4 accM = {0.f, 0.f, 0.f, 0.f};
        f32x4 accL = {0.f, 0.f, 0.f, 0.f};
        #pragma unroll
        for (int ks = 0; ks < 8; ++ks) {
            const short8 b_hi = *(const short8*)(gb + ks * 1024);
            const short8 b_lo = *(const short8*)(gb + ks * 1024 + 512);
            accH = __builtin_amdgcn_mfma_f32_16x16x32_bf16(a_hi[ks], b_hi, accH, 0, 0, 0);
            accM = __builtin_amdgcn_mfma_f32_16x16x32_bf16(a_lo[ks], b_hi, accM, 0, 0, 0);
            accL = __builtin_amdgcn_mfma_f32_16x16x32_bf16(a_hi[ks], b_lo, accL, 0, 0, 0);
        }
        const f32x4 acc = accH + accM + accL;
        #pragma unroll
        for (int r = 0; r < 4; ++r) {
            const int onode = nbase + quad * 4 + r;
            if (onode < NN) {
                const size_t oi = (size_t)onode * H + tile * 16 + nl;
                out[oi] = x[oi] + acc[r];
            }
        }
    }
}

extern "C" void kernel_launch(void* const* d_in, const int* in_sizes, int n_in,
                              void* d_out, int out_size, void* d_ws, size_t ws_size,
                              hipStream_t stream) {
    const float* x   = (const float*)d_in[0];
    const int*   ei  = (const int*)d_in[1];
    const float* ew  = (const float*)d_in[2];
    const float* ea  = (const float*)d_in[3];
    const float* g   = (const float*)d_in[4];
    const float* b   = (const float*)d_in[5];
    const float* Wq  = (const float*)d_in[6];  const float* bq  = (const float*)d_in[7];
    const float* Wk  = (const float*)d_in[8];  const float* bk  = (const float*)d_in[9];
    const float* Wv  = (const float*)d_in[10]; const float* bv  = (const float*)d_in[11];
    const float* Wo  = (const float*)d_in[12]; const float* bo  = (const float*)d_in[13];
    const float* Wdk = (const float*)d_in[14]; const float* bdk = (const float*)d_in[15];
    const float* Wdv = (const float*)d_in[16]; const float* bdv = (const float*)d_in[17];

    unsigned short* q16 = (unsigned short*)d_ws;
    unsigned short* k16 = q16 + (size_t)NN * H;
    unsigned short* v16 = k16 + (size_t)NN * H;
    float* agg  = (float*)(v16 + (size_t)NN * H);
    int*   hist = (int*)(agg + (size_t)NN * H);
    int*   cur  = hist + NN;
    int*   bsum = cur + NN;
    int*   perm = bsum + 128;
    int*   srcs = perm + EE;
    int*   dsts = srcs + EE;
    float* ews  = (float*)(dsts + EE);
    unsigned short* wqkv_p = (unsigned short*)(ews + EE);
    unsigned short* wo_p   = wqkv_p + 393216;
    unsigned short* wdk_p  = wo_p + 131072;    // f16: 16384 ush (dk.h0|dk.h1)
    unsigned short* wdv_p  = wdk_p + 16384;    // f16: 16384 ush (dv.h0|dv.h1)
    float* bias3 = (float*)(wdv_p + 16384);

    hipMemsetAsync(agg, 0, (size_t)NN * H * sizeof(float), stream);
    k_prep<<<226, 256, 0, stream>>>(Wq, Wk, Wv, Wo, g, b, bq, bk, bv, Wdk, Wdv,
                                    wqkv_p, wo_p, wdk_p, wdv_p, bias3, hist);
    k_hist<<<EE / 256, 256, 0, stream>>>(ei, hist);
    k_ln_qkv<<<(NN + 15) / 16, 384, 0, stream>>>(x, wqkv_p, bias3, q16, k16, v16);
    k_scan1<<<NB, 256, 0, stream>>>(hist, cur, bsum);
    k_scan2<<<1, 128, 0, stream>>>(bsum);
    k_scatter<<<EE / 256, 256, 0, stream>>>(ei, ew, cur, bsum, perm, srcs, dsts, ews);
    k_edge<<<GEDGE, 768, 0, stream>>>(q16, k16, v16, ea, wdk_p, bdk, bdv,
                                      perm, srcs, dsts, ews, agg);
    k_out<<<(NN + 15) / 16, 256, 0, stream>>>(agg, wo_p, bo, x, (float*)d_out);
}

// Round 15
// 522.008 us; speedup vs baseline: 1.0579x; 1.0579x over previous
//
#include <hip/hip_runtime.h>
#include <math.h>

#define NN 20000
#define H 256
#define R 64
#define EE 320000
#define LN_EPS 1e-5f
#define NB 79    // ceil(NN/256)
#define GEDGE 256    // k_edge grid: 8 XCDs x 32 blocks, 12 waves each

using short8  = __attribute__((ext_vector_type(8))) short;
using ushort8 = __attribute__((ext_vector_type(8))) unsigned short;
using f32x4   = __attribute__((ext_vector_type(4))) float;
using half8   = __attribute__((ext_vector_type(8))) _Float16;
using half2v  = __attribute__((ext_vector_type(2))) _Float16;

typedef __attribute__((address_space(3))) unsigned int lds_uint;
typedef const __attribute__((address_space(1))) unsigned int glb_uint;

__device__ __forceinline__ float silu_f(float x) {
    return x * __builtin_amdgcn_rcpf(1.0f + __expf(-x));
}

// round-to-nearest-even fp32 -> bf16 (as ushort)
__device__ __forceinline__ unsigned short f2bf(float f) {
    unsigned u = __float_as_uint(f);
    u += 0x7fff + ((u >> 16) & 1);
    return (unsigned short)(u >> 16);
}
__device__ __forceinline__ float bf2f(unsigned short s) {
    return __uint_as_float(((unsigned)s) << 16);
}
// f32 <-> f16 (RNE) via v_cvt
__device__ __forceinline__ unsigned short f2h(float f) {
    unsigned r;
    asm("v_cvt_f16_f32 %0, %1" : "=v"(r) : "v"(f));
    return (unsigned short)r;
}
__device__ __forceinline__ float h2f(unsigned short h) {
    float f;
    asm("v_cvt_f32_f16 %0, %1" : "=v"(f) : "v"((unsigned)h));
    return f;
}

// dks f16 [16][256] per-wave slice: xor col bits[5:4] by row bits[3:2];
// 4-element runs at col%4==0 stay contiguous (XOR touches only bits >= 4).
__device__ __forceinline__ int dh_idx(int row, int col) {
    return row * 256 + (col ^ (((row >> 2) & 3) << 4));
}

// ---------------------------------------------------------------------------
// Combined prep (one launch, 226 blocks)
// ---------------------------------------------------------------------------
__global__ __launch_bounds__(256) void k_prep(
    const float* __restrict__ Wq, const float* __restrict__ Wk,
    const float* __restrict__ Wv, const float* __restrict__ Wo,
    const float* __restrict__ g,  const float* __restrict__ b,
    const float* __restrict__ bq, const float* __restrict__ bk, const float* __restrict__ bv,
    const float* __restrict__ Wdk, const float* __restrict__ Wdv,
    unsigned short* __restrict__ wqkv_p, unsigned short* __restrict__ wo_p,
    unsigned short* __restrict__ wdk_p,  unsigned short* __restrict__ wdv_p,
    float* __restrict__ bias3, int* __restrict__ hist)
{
    const int bid = blockIdx.x, t = threadIdx.x;
    if (bid < 128) {
        const int mat = bid >> 5;
        const float* W = mat == 0 ? Wq : (mat == 1 ? Wk : (mat == 2 ? Wv : Wo));
        unsigned short* out = (mat < 3) ? wqkv_p + (size_t)mat * 131072 : wo_p;
        const int fold = mat < 3;
        const int flat = (bid & 31) * 256 + t;           // [0, 8192)
        const int tile = flat >> 9;
        const int rem  = flat & 511;
        const int ks   = rem >> 6;
        const int lane = rem & 63;
        const int nl = lane & 15, quad = lane >> 4;
        const int h  = tile * 16 + nl;
        const int c0 = ks * 32 + quad * 8;
        short8 hi8, lo8;
        #pragma unroll
        for (int j = 0; j < 8; ++j) {
            float wv = W[(size_t)h * 256 + c0 + j];
            if (fold) wv *= g[c0 + j];
            const unsigned short hh = f2bf(wv);
            hi8[j] = (short)hh;
            lo8[j] = (short)f2bf(wv - bf2f(hh));
        }
        unsigned short* ob = out + ((size_t)(tile * 8 + ks)) * 1024;
        *(short8*)&ob[lane * 8] = hi8;
        *(short8*)&ob[512 + lane * 8] = lo8;
    } else if (bid < 144) {
        // single-f16 pack: value = W[hh*128 + tile*16+nl][ks*32+quad*8+j]
        // at img(mat) + hh*8192 + (tile*2+ks)*512 + lane*8 + j   (f16)
        const int flat = (bid - 128) * 256 + t;          // [0, 4096)
        const int mat  = flat >> 11;
        const int rem  = flat & 2047;
        const int hh   = rem >> 10;
        const int r2   = rem & 1023;
        const int tile = r2 >> 7;
        const int r3   = r2 & 127;
        const int ks   = r3 >> 6;
        const int lane = r3 & 63;
        const int nl = lane & 15, quad = lane >> 4;
        const float* W = mat == 0 ? Wdk : Wdv;
        unsigned short* out = (mat == 0 ? wdk_p : wdv_p)
                            + hh * 8192 + (tile * 2 + ks) * 512 + lane * 8;
        const float* wr = W + (size_t)(hh * 128 + tile * 16 + nl) * 64 + ks * 32 + quad * 8;
        const float4 w0 = *(const float4*)wr;
        const float4 w1 = *(const float4*)(wr + 4);
        const float zz[8] = {w0.x, w0.y, w0.z, w0.w, w1.x, w1.y, w1.z, w1.w};
        ushort8 p8;
        #pragma unroll
        for (int j = 0; j < 8; ++j) p8[j] = f2h(zz[j]);
        *(ushort8*)out = p8;
    } else if (bid < 147) {
        const int mat = bid - 144, h = t;
        const float* W  = mat == 0 ? Wq : (mat == 1 ? Wk : Wv);
        const float* bb = mat == 0 ? bq : (mat == 1 ? bk : bv);
        float s = 0.f;
        const float* wr = W + (size_t)h * 256;
        for (int c = 0; c < 256; c += 4) {
            const float4 w4 = *(const float4*)(wr + c);
            const float4 b4 = *(const float4*)(b + c);
            s += w4.x * b4.x + w4.y * b4.y + w4.z * b4.z + w4.w * b4.w;
        }
        bias3[mat * 256 + h] = bb[h] + s;
    } else {
        const int i = (bid - 147) * 256 + t;
        if (i < NN) hist[i] = 0;
    }
}

// ---------------------------------------------------------------------------
// K1: LayerNorm + QKV. REVERTED to round-19 shape (measured best): 3 waves
// per block, one matrix per wave. Round-20's 6-wave split regressed -13us
// (doubled LN recompute, no weight-stream reduction).
// ---------------------------------------------------------------------------
__global__ __launch_bounds__(192) void k_ln_qkv(
    const float* __restrict__ x,
    const unsigned short* __restrict__ wqkv_p, const float* __restrict__ bias3,
    unsigned short* __restrict__ q, unsigned short* __restrict__ k,
    unsigned short* __restrict__ v)
{
    const int t = threadIdx.x;
    const int wave = t >> 6;             // == mat
    const int lane = t & 63;
    const int nl = lane & 15, quad = lane >> 4;
    const int nbase = blockIdx.x * 16;
    const int node = nbase + nl;
    const bool nv = node < NN;

    float xv[64];
    float sum = 0.f, sq = 0.f;
    {
        const float* xp = x + (size_t)node * H + quad * 8;
        #pragma unroll
        for (int ks = 0; ks < 8; ++ks) {
            float4 x0 = {0.f,0.f,0.f,0.f}, x1 = {0.f,0.f,0.f,0.f};
            if (nv) {
                x0 = *(const float4*)(xp + ks * 32);
                x1 = *(const float4*)(xp + ks * 32 + 4);
            }
            xv[ks*8+0]=x0.x; xv[ks*8+1]=x0.y; xv[ks*8+2]=x0.z; xv[ks*8+3]=x0.w;
            xv[ks*8+4]=x1.x; xv[ks*8+5]=x1.y; xv[ks*8+6]=x1.z; xv[ks*8+7]=x1.w;
            sum += x0.x+x0.y+x0.z+x0.w + x1.x+x1.y+x1.z+x1.w;
            sq  += x0.x*x0.x+x0.y*x0.y+x0.z*x0.z+x0.w*x0.w
                 + x1.x*x1.x+x1.y*x1.y+x1.z*x1.z+x1.w*x1.w;
        }
    }
    sum += __shfl_xor(sum, 16); sum += __shfl_xor(sum, 32);
    sq  += __shfl_xor(sq, 16);  sq  += __shfl_xor(sq, 32);
    const float mu  = sum * (1.0f / H);
    const float var = sq * (1.0f / H) - mu * mu;
    const float rs  = rsqrtf(var + LN_EPS);

    short8 a_hi[8], a_lo[8];
    #pragma unroll
    for (int ks = 0; ks < 8; ++ks) {
        #pragma unroll
        for (int j = 0; j < 8; ++j) {
            const float z = (xv[ks*8+j] - mu) * rs;
            const unsigned short hh = f2bf(z);
            a_hi[ks][j] = (short)hh;
            a_lo[ks][j] = (short)f2bf(z - bf2f(hh));
        }
    }

    const int mat = wave;
    unsigned short* outp = mat == 0 ? q : (mat == 1 ? k : v);
    const float* bp = bias3 + mat * 256;
    const unsigned short* wb = wqkv_p + (size_t)mat * 131072 + lane * 8;
    for (int tile = 0; tile < 16; ++tile) {
        const unsigned short* gb = wb + (size_t)tile * 8192;
        const float bbv = bp[tile * 16 + nl];
        f32x4 accH = {bbv, bbv, bbv, bbv};
        f32x4 accM = {0.f, 0.f, 0.f, 0.f};
        f32x4 accL = {0.f, 0.f, 0.f, 0.f};
        #pragma unroll
        for (int ks = 0; ks < 8; ++ks) {
            const short8 b_hi = *(const short8*)(gb + ks * 1024);
            const short8 b_lo = *(const short8*)(gb + ks * 1024 + 512);
            accH = __builtin_amdgcn_mfma_f32_16x16x32_bf16(a_hi[ks], b_hi, accH, 0, 0, 0);
            accM = __builtin_amdgcn_mfma_f32_16x16x32_bf16(a_lo[ks], b_hi, accM, 0, 0, 0);
            accL = __builtin_amdgcn_mfma_f32_16x16x32_bf16(a_hi[ks], b_lo, accL, 0, 0, 0);
        }
        const f32x4 acc = accH + accM + accL;
        #pragma unroll
        for (int r = 0; r < 4; ++r) {
            const int onode = nbase + quad * 4 + r;
            if (onode < NN)
                outp[(size_t)onode * H + tile * 16 + nl] = f2h(acc[r]);
        }
    }
}

// ---------------------------------------------------------------------------
// Counting sort of edges by dst: hist -> scan -> scatter
// ---------------------------------------------------------------------------
__global__ __launch_bounds__(256) void k_hist(const int* __restrict__ ei, int* __restrict__ hist) {
    int e = blockIdx.x * 256 + threadIdx.x;
    if (e < EE) atomicAdd(&hist[ei[EE + e]], 1);
}

__global__ __launch_bounds__(256) void k_scan1(const int* __restrict__ hist,
                                               int* __restrict__ cursor, int* __restrict__ bsum) {
    const int t = threadIdx.x, i = blockIdx.x * 256 + t;
    const int lane = t & 63, w = t >> 6;
    const int v = (i < NN) ? hist[i] : 0;
    int incl = v;
    #pragma unroll
    for (int off = 1; off < 64; off <<= 1) {
        int u = __shfl_up(incl, off);
        if (lane >= off) incl += u;
    }
    __shared__ int ws[4];
    if (lane == 63) ws[w] = incl;
    __syncthreads();
    int base = 0;
    #pragma unroll
    for (int j = 0; j < 4; ++j) if (j < w) base += ws[j];
    if (i < NN) cursor[i] = base + incl - v;
    if (t == 255) bsum[blockIdx.x] = base + incl;
}

__global__ __launch_bounds__(128) void k_scan2(int* __restrict__ bsum) {
    __shared__ int buf[128];
    const int t = threadIdx.x;
    const int v = (t < NB) ? bsum[t] : 0;
    buf[t] = v;
    __syncthreads();
    #pragma unroll
    for (int off = 1; off < 128; off <<= 1) {
        int add = (t >= off) ? buf[t - off] : 0;
        __syncthreads();
        buf[t] += add;
        __syncthreads();
    }
    if (t < NB) bsum[t] = buf[t] - v;
}

// scatter also materializes sorted src/dst/ew streams.
__global__ __launch_bounds__(256) void k_scatter(const int* __restrict__ ei,
                                                 const float* __restrict__ ew,
                                                 int* __restrict__ cursor,
                                                 const int* __restrict__ bsum,
                                                 int* __restrict__ perm,
                                                 int* __restrict__ srcs,
                                                 int* __restrict__ dsts,
                                                 float* __restrict__ ews) {
    int e = blockIdx.x * 256 + threadIdx.x;
    if (e < EE) {
        int s = ei[e];
        int d = ei[EE + e];
        int pos = atomicAdd(&cursor[d], 1) + bsum[d >> 8];
        perm[pos] = e;
        srcs[pos] = s;
        dsts[pos] = d;
        ews[pos] = ew[e];
    }
}

// ---------------------------------------------------------------------------
// K2 round-21: r19 structure + pass-A REGISTER PREFETCH. r7's prefetch died
// by spill at VGPR 120+64; now base VGPR=84, f16 halves the footprint:
// 8 k-rows + 8 q-rows = 64 VGPRs as uint2 pairs -> ~148, under the ~170 cap
// for 3 waves/SIMD. Index loads + q/k row loads issue BEFORE the two dk
// MFMA phases (~1-2Kcy of LDS+MFMA work) -> pass A is register+LDS only.
// v-prefetch deliberately skipped (would exceed the VGPR cap).
// Spill detector: WRITE_SIZE must stay exactly 230,088 KB.
// ---------------------------------------------------------------------------
__global__ __launch_bounds__(768, 3) void k_edge(
    const unsigned short* __restrict__ q16, const unsigned short* __restrict__ k16,
    const unsigned short* __restrict__ v16,
    const float* __restrict__ ea,
    const unsigned short* __restrict__ wdkv_p,   // wdk(16384) | wdv(16384) f16
    const float* __restrict__ bdk, const float* __restrict__ bdv,
    const int* __restrict__ perm, const int* __restrict__ srcs,
    const int* __restrict__ dsts, const float* __restrict__ ews,
    float* __restrict__ agg)
{
    __shared__ __align__(16) unsigned short wlds[4 * 8192];         // 64 KB
    __shared__ __align__(16) unsigned short dks_all[12 * 16 * 256]; // 96 KB

    const int t    = threadIdx.x;
    const int bi   = blockIdx.x;
    const int wave = t >> 6, lane = t & 63;
    const int nl = lane & 15, quad = lane >> 4;
    const int tx = lane & 31, ty2 = lane >> 5;
    const int h0 = tx * 4, e0l = ty2 * 8;

    // bijective XCD mapping: 256 blocks = 8 XCDs x 32; XCD x owns a
    // contiguous strip range (strip = 16 sorted edges; 20000 strips total,
    // first 32 wgids get 79 strips, rest 78).
    const int xcd = bi & 7, jj = bi >> 3;
    const int wgid = xcd * 32 + jj;
    const int sbase  = wgid * 78 + (wgid < 32 ? wgid : 32);
    const int scount = 78 + (wgid < 32 ? 1 : 0);

    unsigned short* dksw = dks_all + wave * 4096;

    // ---- stage all 64KB of weight images once ----
    {
        const ushort8* sp = (const ushort8*)wdkv_p + (t & 255);
        ushort8* dpw = (ushort8*)wlds + (t & 192);   // wave-uniform base
        if (t < 256) {
            #pragma unroll
            for (int c = 0; c < 16; ++c)
                __builtin_amdgcn_global_load_lds((glb_uint*)(sp + c * 256),
                                                 (lds_uint*)(dpw + c * 256), 16, 0, 0);
        }
    }
    __syncthreads();   // the ONLY block-wide barrier

    #define MFMA_DKS16(IMG, BIAS, HALF)                                               \
    {                                                                                 \
        const unsigned short* ib_ = wlds + (IMG) * 8192;                              \
        f32x4 accA[8];                                                                \
        _Pragma("unroll")                                                             \
        for (int tt = 0; tt < 8; ++tt) {                                              \
            const half8 b0 = *(const half8*)&ib_[(tt * 2 + 0) * 512 + lane * 8];      \
            const half8 b1 = *(const half8*)&ib_[(tt * 2 + 1) * 512 + lane * 8];      \
            const float bb = (BIAS)[(HALF) * 128 + tt * 16 + nl];                     \
            f32x4 acc = {bb, bb, bb, bb};                                             \
            acc = __builtin_amdgcn_mfma_f32_16x16x32_f16(af0, b0, acc, 0, 0, 0);      \
            acc = __builtin_amdgcn_mfma_f32_16x16x32_f16(af1, b1, acc, 0, 0, 0);      \
            accA[tt] = acc;                                                           \
        }                                                                             \
        _Pragma("unroll")                                                             \
        for (int tt = 0; tt < 8; ++tt)                                                \
            _Pragma("unroll")                                                         \
            for (int r = 0; r < 4; ++r)                                               \
                dksw[dh_idx(quad * 4 + r, (HALF) * 128 + tt * 16 + nl)] =             \
                    f2h(silu_f(accA[tt][r]));                                         \
    }

    // ---- up to 7 strip-iterations; per-wave independent, barrier-free ----
    for (int it = 0; it < 7; ++it) {
        const int sl = it * 12 + wave;
        if (sl >= scount) continue;
        const int eb2 = (sbase + sl) * 16;   // this wave's 16 edges

        // indices early (L2-hot sorted streams)
        int srcr[8], dstr[8];
        #pragma unroll
        for (int i = 0; i < 8; ++i) {
            srcr[i] = srcs[eb2 + e0l + i];
            dstr[i] = dsts[eb2 + e0l + i];
        }

        // ea A-fragments as f16 (row nl = own edge)
        half8 af0, af1;
        {
            const int e = perm[eb2 + nl];
            const float* ap = ea + (size_t)e * R + quad * 8;
            const f32x4 x0 = *(const f32x4*)(ap);
            const f32x4 x1 = *(const f32x4*)(ap + 4);
            const f32x4 x2 = *(const f32x4*)(ap + 32);
            const f32x4 x3 = *(const f32x4*)(ap + 36);
            #pragma unroll
            for (int j2 = 0; j2 < 4; ++j2) {
                af0[j2]     = (_Float16)x0[j2];
                af0[j2 + 4] = (_Float16)x1[j2];
                af1[j2]     = (_Float16)x2[j2];
                af1[j2 + 4] = (_Float16)x3[j2];
            }
        }

        // PREFETCH: k and q rows for my 8 edges -- land under the dk phases
        uint2 kp0[8], kp1[8], qp0[8], qp1[8];
        #pragma unroll
        for (int i = 0; i < 8; ++i) {
            const int s = srcr[i], d = dstr[i];
            kp0[i] = *(const uint2*)(k16 + (size_t)s * H + h0);
            kp1[i] = *(const uint2*)(k16 + (size_t)s * H + 128 + h0);
            qp0[i] = *(const uint2*)(q16 + (size_t)d * H + h0);
            qp1[i] = *(const uint2*)(q16 + (size_t)d * H + 128 + h0);
        }

        MFMA_DKS16(0, bdk, 0);
        MFMA_DKS16(1, bdk, 1);

        // ---- pass A: pure register+LDS; result reduced into every lane ----
        float att[8];
        #pragma unroll
        for (int i = 0; i < 8; ++i) {
            const uint2 dd0 = *(const uint2*)&dksw[dh_idx(e0l + i, h0)];
            const uint2 dd1 = *(const uint2*)&dksw[dh_idx(e0l + i, 128 + h0)];
            float part = 0.f;
            part = __builtin_amdgcn_fdot2(__builtin_bit_cast(half2v, qp0[i].x) *
                                          __builtin_bit_cast(half2v, kp0[i].x),
                                          __builtin_bit_cast(half2v, dd0.x), part, false);
            part = __builtin_amdgcn_fdot2(__builtin_bit_cast(half2v, qp0[i].y) *
                                          __builtin_bit_cast(half2v, kp0[i].y),
                                          __builtin_bit_cast(half2v, dd0.y), part, false);
            part = __builtin_amdgcn_fdot2(__builtin_bit_cast(half2v, qp1[i].x) *
                                          __builtin_bit_cast(half2v, kp1[i].x),
                                          __builtin_bit_cast(half2v, dd1.x), part, false);
            part = __builtin_amdgcn_fdot2(__builtin_bit_cast(half2v, qp1[i].y) *
                                          __builtin_bit_cast(half2v, kp1[i].y),
                                          __builtin_bit_cast(half2v, dd1.y), part, false);
            #pragma unroll
            for (int off = 16; off; off >>= 1) part += __shfl_xor(part, off);
            att[i] = part;   // xor-reduce: every lane holds the sum
        }

        // finalize attn (redundant per lane; ews is an L2-hot sorted stream)
        #pragma unroll
        for (int i = 0; i < 8; ++i) {
            const float rr = ews[eb2 + e0l + i];
            const float cut = (rr < 5.0f) ? 0.5f * (__cosf(rr * 0.6283185307f) + 1.0f) : 0.0f;
            att[i] = silu_f(att[i]) * cut;
        }

        MFMA_DKS16(2, bdv, 0);
        MFMA_DKS16(3, bdv, 1);

        // ---- pass B: f16 v gathers, run-flush row-walk over 256 cols ----
        {
            float4 m0 = {0.f,0.f,0.f,0.f}, m1 = {0.f,0.f,0.f,0.f};
            int cur_d = -1;
            #pragma unroll
            for (int i = 0; i < 8; ++i) {
                const int d = dstr[i], s = srcr[i];
                const float a = att[i];
                const uint2 vv0 = *(const uint2*)(v16 + (size_t)s * H + h0);
                const uint2 vv1 = *(const uint2*)(v16 + (size_t)s * H + 128 + h0);
                const uint2 dd0 = *(const uint2*)&dksw[dh_idx(e0l + i, h0)];
                const uint2 dd1 = *(const uint2*)&dksw[dh_idx(e0l + i, 128 + h0)];
                const half2v w0 = __builtin_bit_cast(half2v, vv0.x) * __builtin_bit_cast(half2v, dd0.x);
                const half2v w1 = __builtin_bit_cast(half2v, vv0.y) * __builtin_bit_cast(half2v, dd0.y);
                const half2v w2 = __builtin_bit_cast(half2v, vv1.x) * __builtin_bit_cast(half2v, dd1.x);
                const half2v w3 = __builtin_bit_cast(half2v, vv1.y) * __builtin_bit_cast(half2v, dd1.y);
                if (d != cur_d) {
                    if (cur_d >= 0) {
                        float* dp = agg + (size_t)cur_d * H;
                        atomicAdd(dp + h0 + 0, m0.x); atomicAdd(dp + h0 + 1, m0.y);
                        atomicAdd(dp + h0 + 2, m0.z); atomicAdd(dp + h0 + 3, m0.w);
                        atomicAdd(dp + 128 + h0 + 0, m1.x); atomicAdd(dp + 128 + h0 + 1, m1.y);
                        atomicAdd(dp + 128 + h0 + 2, m1.z); atomicAdd(dp + 128 + h0 + 3, m1.w);
                    }
                    m0.x = (float)w0[0] * a; m0.y = (float)w0[1] * a;
                    m0.z = (float)w1[0] * a; m0.w = (float)w1[1] * a;
                    m1.x = (float)w2[0] * a; m1.y = (float)w2[1] * a;
                    m1.z = (float)w3[0] * a; m1.w = (float)w3[1] * a;
                    cur_d = d;
                } else {
                    m0.x += (float)w0[0] * a; m0.y += (float)w0[1] * a;
                    m0.z += (float)w1[0] * a; m0.w += (float)w1[1] * a;
                    m1.x += (float)w2[0] * a; m1.y += (float)w2[1] * a;
                    m1.z += (float)w3[0] * a; m1.w += (float)w3[1] * a;
                }
            }
            {
                float* dp = agg + (size_t)cur_d * H;
                atomicAdd(dp + h0 + 0, m0.x); atomicAdd(dp + h0 + 1, m0.y);
                atomicAdd(dp + h0 + 2, m0.z); atomicAdd(dp + h0 + 3, m0.w);
                atomicAdd(dp + 128 + h0 + 0, m1.x); atomicAdd(dp + 128 + h0 + 1, m1.y);
                atomicAdd(dp + 128 + h0 + 2, m1.z); atomicAdd(dp + 128 + h0 + 3, m1.w);
            }
        }
    }
    #undef MFMA_DKS16
}

// ---------------------------------------------------------------------------
// K3: out = x + agg @ Wo'^T + bo. REVERTED to round-19 shape (measured best):
// 2 waves per block, 8 tiles each.
// ---------------------------------------------------------------------------
__global__ __launch_bounds__(128) void k_out(
    const float* __restrict__ aggm, const unsigned short* __restrict__ wo_p,
    const float* __restrict__ bo, const float* __restrict__ x, float* __restrict__ out)
{
    const int t = threadIdx.x;
    const int wave = t >> 6;
    const int lane = t & 63;
    const int nl = lane & 15, quad = lane >> 4;
    const int nbase = blockIdx.x * 16;
    const int node = nbase + nl;
    const bool nv = node < NN;

    short8 a_hi[8], a_lo[8];
    {
        const float* ap = aggm + (size_t)node * H + quad * 8;
        #pragma unroll
        for (int ks = 0; ks < 8; ++ks) {
            float4 x0 = {0.f,0.f,0.f,0.f}, x1 = {0.f,0.f,0.f,0.f};
            if (nv) { x0 = *(const float4*)(ap + ks * 32); x1 = *(const float4*)(ap + ks * 32 + 4); }
            const float zz[8] = {x0.x,x0.y,x0.z,x0.w,x1.x,x1.y,x1.z,x1.w};
            #pragma unroll
            for (int j = 0; j < 8; ++j) {
                const unsigned short hh = f2bf(zz[j]);
                a_hi[ks][j] = (short)hh;
                a_lo[ks][j] = (short)f2bf(zz[j] - bf2f(hh));
            }
        }
    }
    for (int tile = wave * 8; tile < wave * 8 + 8; ++tile) {
        const unsigned short* gb = wo_p + (size_t)tile * 8192 + lane * 8;
        const float bbv = bo[tile * 16 + nl];
        f32x4 accH = {bbv, bbv, bbv, bbv};
        f32x4 accM = {0.f, 0.f, 0.f, 0.f};
        f32x4 accL = {0.f, 0.f, 0.f, 0.f};
        #pragma unroll
        for (int ks = 0; ks < 8; ++ks) {
            const short8 b_hi = *(const short8*)(gb + ks * 1024);
            const short8 b_lo = *(const short8*)(gb + ks * 1024 + 512);
            accH = __builtin_amdgcn_mfma_f32_16x16x32_bf16(a_hi[ks], b_hi, accH, 0, 0, 0);
            accM = __builtin_amdgcn_mfma_f32_16x16x32_bf16(a_lo[ks], b_hi, accM, 0, 0, 0);
            accL = __builtin_amdgcn_mfma_f32_16x16x32_bf16(a_hi[ks], b_lo, accL, 0, 0, 0);
        }
        const f32x4 acc = accH + accM + accL;
        #pragma unroll
        for (int r = 0; r < 4; ++r) {
            const int onode = nbase + quad * 4 + r;
            if (onode < NN) {
                const size_t oi = (size_t)onode * H + tile * 16 + nl;
                out[oi] = x[oi] + acc[r];
            }
        }
    }
}

extern "C" void kernel_launch(void* const* d_in, const int* in_sizes, int n_in,
                              void* d_out, int out_size, void* d_ws, size_t ws_size,
                              hipStream_t stream) {
    const float* x   = (const float*)d_in[0];
    const int*   ei  = (const int*)d_in[1];
    const float* ew  = (const float*)d_in[2];
    const float* ea  = (const float*)d_in[3];
    const float* g   = (const float*)d_in[4];
    const float* b   = (const float*)d_in[5];
    const float* Wq  = (const float*)d_in[6];  const float* bq  = (const float*)d_in[7];
    const float* Wk  = (const float*)d_in[8];  const float* bk  = (const float*)d_in[9];
    const float* Wv  = (const float*)d_in[10]; const float* bv  = (const float*)d_in[11];
    const float* Wo  = (const float*)d_in[12]; const float* bo  = (const float*)d_in[13];
    const float* Wdk = (const float*)d_in[14]; const float* bdk = (const float*)d_in[15];
    const float* Wdv = (const float*)d_in[16]; const float* bdv = (const float*)d_in[17];

    unsigned short* q16 = (unsigned short*)d_ws;
    unsigned short* k16 = q16 + (size_t)NN * H;
    unsigned short* v16 = k16 + (size_t)NN * H;
    float* agg  = (float*)(v16 + (size_t)NN * H);
    int*   hist = (int*)(agg + (size_t)NN * H);
    int*   cur  = hist + NN;
    int*   bsum = cur + NN;
    int*   perm = bsum + 128;
    int*   srcs = perm + EE;
    int*   dsts = srcs + EE;
    float* ews  = (float*)(dsts + EE);
    unsigned short* wqkv_p = (unsigned short*)(ews + EE);
    unsigned short* wo_p   = wqkv_p + 393216;
    unsigned short* wdk_p  = wo_p + 131072;    // f16: 16384 ush (dk.h0|dk.h1)
    unsigned short* wdv_p  = wdk_p + 16384;    // f16: 16384 ush (dv.h0|dv.h1)
    float* bias3 = (float*)(wdv_p + 16384);

    hipMemsetAsync(agg, 0, (size_t)NN * H * sizeof(float), stream);
    k_prep<<<226, 256, 0, stream>>>(Wq, Wk, Wv, Wo, g, b, bq, bk, bv, Wdk, Wdv,
                                    wqkv_p, wo_p, wdk_p, wdv_p, bias3, hist);
    k_hist<<<EE / 256, 256, 0, stream>>>(ei, hist);
    k_ln_qkv<<<(NN + 15) / 16, 192, 0, stream>>>(x, wqkv_p, bias3, q16, k16, v16);
    k_scan1<<<NB, 256, 0, stream>>>(hist, cur, bsum);
    k_scan2<<<1, 128, 0, stream>>>(bsum);
    k_scatter<<<EE / 256, 256, 0, stream>>>(ei, ew, cur, bsum, perm, srcs, dsts, ews);
    k_edge<<<GEDGE, 768, 0, stream>>>(q16, k16, v16, ea, wdk_p, bdk, bdv,
                                      perm, srcs, dsts, ews, agg);
    k_out<<<(NN + 15) / 16, 128, 0, stream>>>(agg, wo_p, bo, x, (float*)d_out);
}